// Round 6
// baseline (306.049 us; speedup 1.0000x reference)
//
#include <hip/hip_runtime.h>
#include <math.h>

constexpr int H = 512, W = 512;
constexpr int N_ANGLES = 360;
constexpr int N_DET = 736;
constexpr int N_STEPS = 725;                 // ceil(hypot(512,512))
constexpr int SINO_SIZE = N_ANGLES * N_DET;  // 264960

constexpr int DET_TILE = 64;
constexpr int K_TILE   = 64;
constexpr int PITCH    = 106;  // even (float2 writes); 106 mod 32 = 10 -> 2-way max conflicts
constexpr int ROWS     = 94;   // max bh = 93 (hy <= 45.05 -> 2*45.05+2)
constexpr int CHUNKS   = PITCH / 2;          // 53 float2 per row
constexpr int MAXPRE   = 10;                 // ceil(94*53/512)
// LDS: 94*106*4 = 39856 B -> 4 blocks/CU (159.4 KB of 160) @ 512 thr = 32 waves/CU

// ---------------------------------------------------------------------------
// Kernel 1: updated_reco = x + reco
// ---------------------------------------------------------------------------
__global__ void add_kernel(const float4* __restrict__ x,
                           const float4* __restrict__ reco,
                           float4* __restrict__ out) {
    int i = blockIdx.x * blockDim.x + threadIdx.x;
    float4 a = x[i];
    float4 b = reco[i];
    out[i] = make_float4(a.x + b.x, a.y + b.y, a.z + b.z, a.w + b.w);
}

// ---------------------------------------------------------------------------
// Kernel 2: forward projection, zero-border LDS tiles, branch-free inner loop,
// register-prefetched staging (next tile's global loads issued before the
// current tile's sample loop -> HBM/L2 latency hidden under compute).
// Block = (angle, 64 detectors), 512 threads.
// Wave footprint: 16 detectors x 4 k-steps.
// ---------------------------------------------------------------------------
__global__ __launch_bounds__(512, 8) void radon_kernel(const float* __restrict__ img,
                                                       const float* __restrict__ angles,
                                                       float* __restrict__ sino) {
    __shared__ float tile[ROWS * PITCH];

    const int tid = threadIdx.x;
    const int w   = tid >> 6;
    const int l   = tid & 63;
    const int dt_ = 16 * (w & 3) + (l & 15);   // detector within tile
    const int klr = 4 * (w >> 2) + (l >> 4);   // k residue 0..7
    const int a   = blockIdx.y;
    const int d0  = blockIdx.x * DET_TILE;

    const float theta = angles[a];
    const float c = cosf(theta);
    const float s = sinf(theta);
    const float ac = fabsf(c), as = fabsf(s);
    const float cx = (W - 1) * 0.5f;            // 255.5
    const float cy = (H - 1) * 0.5f;            // 255.5
    const float t_off = (N_STEPS - 1) * 0.5f;   // 362

    const float u   = (float)(d0 + dt_) - (N_DET - 1) * 0.5f;
    const float bxu = cx - s * u;               // px = c*t + bxu
    const float byu = cy + c * u;               // py = s*t + byu

    // ---- conservative block k-window via interval arithmetic over u ----
    const float uLo = (float)d0 - (N_DET - 1) * 0.5f;
    const float uHi = uLo + (DET_TILE - 1);
    float su0 = s * uLo, su1 = s * uHi;
    float smin = fminf(su0, su1), smax = fmaxf(su0, su1);
    float cu0 = c * uLo, cu1 = c * uHi;
    float cmin = fminf(cu0, cu1), cmax = fmaxf(cu0, cu1);

    float tmin = -1e30f, tmax = 1e30f;
    {   // exists u: px in (-1, W)  <=>  c*t in (xlo, xhi)
        float xlo = -1.0f - cx + smin;
        float xhi = (float)W - cx + smax;
        if (ac > 1e-12f) {
            float t0 = xlo / c, t1 = xhi / c;
            tmin = fmaxf(tmin, fminf(t0, t1));
            tmax = fminf(tmax, fmaxf(t0, t1));
        } else if (xlo > 0.0f || xhi < 0.0f) {
            tmax = -2e30f;
        }
    }
    {   // exists u: py in (-1, H)  <=>  s*t in (ylo, yhi)
        float ylo = -1.0f - cy - cmax;
        float yhi = (float)H - cy - cmin;
        if (as > 1e-12f) {
            float t0 = ylo / s, t1 = yhi / s;
            tmin = fmaxf(tmin, fminf(t0, t1));
            tmax = fminf(tmax, fmaxf(t0, t1));
        } else if (ylo > 0.0f || yhi < 0.0f) {
            tmax = -2e30f;
        }
    }
    const int kminU = (int)fminf(725.0f, fmaxf(0.0f, ceilf(tmin + t_off) - 1.0f));
    const int kmaxU = (int)fmaxf(-1.0f, fminf((float)(N_STEPS - 1), floorf(tmax + t_off) + 1.0f));

    const float ucf = uLo + 0.5f * (DET_TILE - 1);
    const float dx8 = 8.0f * c;
    const float dy8 = 8.0f * s;

    // ---- bbox + register prefetch machinery ----
    int cx0 = 0, cy0 = 0, ctotal = 0;
    float2 pre[MAXPRE];
    int pidx[MAXPRE];

    auto compute_bbox = [&](int k0) {
        const int k1 = min(k0 + K_TILE - 1, kmaxU);
        const float t0f = (float)k0 - t_off;
        const float dt  = (float)(k1 - k0);
        const float tc  = t0f + 0.5f * dt;
        const float xc_ = fmaf(c, tc, cx) - s * ucf;
        const float yc_ = fmaf(s, tc, cy) + c * ucf;
        const float hx = fmaf(0.5f * ac, dt, 0.5f * (DET_TILE - 1) * as) + 0.5f;
        const float hy = fmaf(0.5f * as, dt, 0.5f * (DET_TILE - 1) * ac) + 0.5f;
        cx0 = ((int)floorf(xc_ - hx)) & ~1;              // even -> 8B-aligned chunks
        cy0 = (int)floorf(yc_ - hy);
        const int bh = min((int)floorf(yc_ + hy) + 1 - cy0 + 1, ROWS);
        ctotal = bh * CHUNKS;
    };

    auto prefetch = [&]() {
        #pragma unroll
        for (int j = 0; j < MAXPRE; ++j) {
            const int i = tid + j * 512;
            float2 v = make_float2(0.0f, 0.0f);
            int idx = -1;
            if (i < ctotal) {
                const int r  = i / CHUNKS;               // const-divisor magic mul
                const int ch = i - r * CHUNKS;
                const int gx = cx0 + 2 * ch;
                const int gy = cy0 + r;
                idx = r * PITCH + 2 * ch;
                if ((unsigned)gy < (unsigned)H) {
                    const float* rowp = img + gy * W;
                    if (gx >= 0 && gx + 1 < W) {
                        v = *(const float2*)(rowp + gx);
                    } else {
                        if ((unsigned)gx < (unsigned)W)       v.x = rowp[gx];
                        if ((unsigned)(gx + 1) < (unsigned)W) v.y = rowp[gx + 1];
                    }
                }
            }
            pre[j] = v;
            pidx[j] = idx;
        }
    };

    float acc = 0.0f;

    if (kminU <= kmaxU) {
        compute_bbox(kminU);
        prefetch();

        for (int k0 = kminU; k0 <= kmaxU; k0 += K_TILE) {
            __syncthreads();                  // previous sampling done, LDS free
            // ---- commit prefetched chunks to LDS ----
            #pragma unroll
            for (int j = 0; j < MAXPRE; ++j) {
                if (pidx[j] >= 0)
                    *(float2*)(tile + pidx[j]) = pre[j];
            }
            __syncthreads();

            // capture sampling params for CURRENT tile before bbox overwrite
            const int k1  = min(k0 + K_TILE - 1, kmaxU);
            const int kst = k0 + klr;
            float px = fmaf(c, (float)kst - t_off, bxu) - (float)cx0;
            float py = fmaf(s, (float)kst - t_off, byu) - (float)cy0;

            // issue next tile's loads now; they fly during the sample loop
            if (k0 + K_TILE <= kmaxU) {
                compute_bbox(k0 + K_TILE);
                prefetch();
            }

            // ---- branch-free sampling from LDS ----
            // px,py >= 0 by bbox construction -> (int) truncation == floor
            #pragma unroll 4
            for (int k = kst; k <= k1; k += 8) {
                int xi = (int)px;
                int yi = (int)py;
                float wx = px - floorf(px);
                float wy = py - floorf(py);
                int idx = __mul24(yi, PITCH) + xi;
                float v00 = tile[idx];
                float v01 = tile[idx + 1];          // ds_read2_b32 (0,1)
                float v10 = tile[idx + PITCH];
                float v11 = tile[idx + PITCH + 1];  // ds_read2_b32 (106,107)
                float top = fmaf(wx, v01 - v00, v00);
                float bot = fmaf(wx, v11 - v10, v10);
                acc = fmaf(wy, bot - top, acc + top);
                px += dx8;
                py += dy8;
            }
        }
        __syncthreads();   // protect tile reuse below
    }

    // ---- reduce 8 k-residues per detector ----
    acc += __shfl_xor(acc, 16);
    acc += __shfl_xor(acc, 32);
    float* scratch = tile;
    if (l < 16) scratch[w * 16 + l] = acc;
    __syncthreads();
    if (tid < DET_TILE) {
        int g  = tid >> 4;
        int dd = tid & 15;
        float r = scratch[g * 16 + dd] + scratch[(g + 4) * 16 + dd];
        int dglob = d0 + tid;
        if (dglob < N_DET) sino[a * N_DET + dglob] = r;   // last block: d0=704, dets 736..767 are phantom
    }
}

// ---------------------------------------------------------------------------
extern "C" void kernel_launch(void* const* d_in, const int* in_sizes, int n_in,
                              void* d_out, int out_size, void* d_ws, size_t ws_size,
                              hipStream_t stream) {
    const float* x      = (const float*)d_in[0];
    const float* reco   = (const float*)d_in[1];
    const float* angles = (const float*)d_in[2];

    float* sino    = (float*)d_out;              // (360, 736)
    float* updated = (float*)d_out + SINO_SIZE;  // (512, 512)

    int n4 = (H * W) / 4;
    add_kernel<<<n4 / 256, 256, 0, stream>>>(
        (const float4*)x, (const float4*)reco, (float4*)updated);

    dim3 grid((N_DET + DET_TILE - 1) / DET_TILE, N_ANGLES);   // (12, 360)
    radon_kernel<<<grid, 512, 0, stream>>>(updated, angles, sino);
}

// Round 7
// 174.041 us; speedup vs baseline: 1.7585x; 1.7585x over previous
//
#include <hip/hip_runtime.h>
#include <math.h>

constexpr int H = 512, W = 512;
constexpr int N_ANGLES = 360;
constexpr int N_DET = 736;
constexpr int N_STEPS = 725;                 // ceil(hypot(512,512))
constexpr int SINO_SIZE = N_ANGLES * N_DET;  // 264960

constexpr int DET_TILE = 64;
constexpr int K_TILE   = 64;
constexpr int PITCH    = 106;  // even (float2 writes); < 256 so ds_read2 offset1 fits
constexpr int ROWS     = 94;   // max bh = 93 (hy <= 45.05 -> 2*45.05+2)
constexpr int CHUNKS   = PITCH / 2;          // 53 float2 per row
// LDS: 94*106*4 = 39856 B -> 4 blocks/CU (159.4 KB of 160) @ 512 thr = 32 waves/CU

typedef float v2f __attribute__((ext_vector_type(2)));

// ---------------------------------------------------------------------------
// Kernel 1: updated_reco = x + reco
// ---------------------------------------------------------------------------
__global__ void add_kernel(const float4* __restrict__ x,
                           const float4* __restrict__ reco,
                           float4* __restrict__ out) {
    int i = blockIdx.x * blockDim.x + threadIdx.x;
    float4 a = x[i];
    float4 b = reco[i];
    out[i] = make_float4(a.x + b.x, a.y + b.y, a.z + b.z, a.w + b.w);
}

// ---------------------------------------------------------------------------
// Kernel 2: forward projection, zero-border LDS tiles, branch-free inner loop.
// Block = (angle, 64 detectors), 512 threads; wave footprint 16 det x 4 k.
// Inner loop: column-pair ds_read2 (v00,v10)/(v01,v11) + packed-f32 lerp.
// Direct two-barrier staging (round-4 structure; NO register prefetch -> no
// spill: round 6 showed 747 MB of scratch FETCH from pre[]/pidx[] spilling).
// ---------------------------------------------------------------------------
__global__ __launch_bounds__(512, 8) void radon_kernel(const float* __restrict__ img,
                                                       const float* __restrict__ angles,
                                                       float* __restrict__ sino) {
    __shared__ float tile[ROWS * PITCH];

    const int tid = threadIdx.x;
    const int w   = tid >> 6;
    const int l   = tid & 63;
    const int dt_ = 16 * (w & 3) + (l & 15);   // detector within tile
    const int klr = 4 * (w >> 2) + (l >> 4);   // k residue 0..7
    const int a   = blockIdx.y;
    const int d0  = blockIdx.x * DET_TILE;

    const float theta = angles[a];
    const float c = cosf(theta);
    const float s = sinf(theta);
    const float ac = fabsf(c), as = fabsf(s);
    const float cx = (W - 1) * 0.5f;            // 255.5
    const float cy = (H - 1) * 0.5f;            // 255.5
    const float t_off = (N_STEPS - 1) * 0.5f;   // 362

    const float u   = (float)(d0 + dt_) - (N_DET - 1) * 0.5f;
    const float bxu = cx - s * u;               // px = c*t + bxu
    const float byu = cy + c * u;               // py = s*t + byu

    // ---- conservative block k-window via interval arithmetic over u ----
    const float uLo = (float)d0 - (N_DET - 1) * 0.5f;
    const float uHi = uLo + (DET_TILE - 1);
    float su0 = s * uLo, su1 = s * uHi;
    float smin = fminf(su0, su1), smax = fmaxf(su0, su1);
    float cu0 = c * uLo, cu1 = c * uHi;
    float cmin = fminf(cu0, cu1), cmax = fmaxf(cu0, cu1);

    float tmin = -1e30f, tmax = 1e30f;
    {   // exists u: px in (-1, W)  <=>  c*t in (xlo, xhi)
        float xlo = -1.0f - cx + smin;
        float xhi = (float)W - cx + smax;
        if (ac > 1e-12f) {
            float t0 = xlo / c, t1 = xhi / c;
            tmin = fmaxf(tmin, fminf(t0, t1));
            tmax = fminf(tmax, fmaxf(t0, t1));
        } else if (xlo > 0.0f || xhi < 0.0f) {
            tmax = -2e30f;
        }
    }
    {   // exists u: py in (-1, H)  <=>  s*t in (ylo, yhi)
        float ylo = -1.0f - cy - cmax;
        float yhi = (float)H - cy - cmin;
        if (as > 1e-12f) {
            float t0 = ylo / s, t1 = yhi / s;
            tmin = fmaxf(tmin, fminf(t0, t1));
            tmax = fminf(tmax, fmaxf(t0, t1));
        } else if (ylo > 0.0f || yhi < 0.0f) {
            tmax = -2e30f;
        }
    }
    const int kminU = (int)fminf(725.0f, fmaxf(0.0f, ceilf(tmin + t_off) - 1.0f));
    const int kmaxU = (int)fmaxf(-1.0f, fminf((float)(N_STEPS - 1), floorf(tmax + t_off) + 1.0f));

    const float ucf = uLo + 0.5f * (DET_TILE - 1);
    const v2f dinc = {8.0f * c, 8.0f * s};

    float acc = 0.0f;

    for (int k0 = kminU; k0 <= kmaxU; k0 += K_TILE) {
        const int k1 = min(k0 + K_TILE - 1, kmaxU);
        // ---- bbox of ALL sample positions for (u in tile, t in [t0,t1]) ----
        const float t0f = (float)k0 - t_off;
        const float dt  = (float)(k1 - k0);
        const float tc  = t0f + 0.5f * dt;
        const float xc_ = fmaf(c, tc, cx) - s * ucf;
        const float yc_ = fmaf(s, tc, cy) + c * ucf;
        const float hx = fmaf(0.5f * ac, dt, 0.5f * (DET_TILE - 1) * as) + 0.5f;
        const float hy = fmaf(0.5f * as, dt, 0.5f * (DET_TILE - 1) * ac) + 0.5f;
        const int x0 = ((int)floorf(xc_ - hx)) & ~1;     // even -> 8B-aligned chunks
        const int y0 = (int)floorf(yc_ - hy);
        const int bh = min((int)floorf(yc_ + hy) + 1 - y0 + 1, ROWS);

        // ---- stage bbox rows as float2 chunks; 0 outside the image ----
        {
            const int total = bh * CHUNKS;
            for (int i = tid; i < total; i += 512) {
                int r  = i / CHUNKS;                // const-divisor magic mul
                int ch = i - r * CHUNKS;
                int gx = x0 + 2 * ch;
                int gy = y0 + r;
                float2 v = make_float2(0.0f, 0.0f);
                if ((unsigned)gy < (unsigned)H) {
                    const float* rowp = img + gy * W;
                    if (gx >= 0 && gx + 1 < W) {
                        v = *(const float2*)(rowp + gx);
                    } else {
                        if ((unsigned)gx < (unsigned)W)       v.x = rowp[gx];
                        if ((unsigned)(gx + 1) < (unsigned)W) v.y = rowp[gx + 1];
                    }
                }
                *(float2*)(tile + r * PITCH + 2 * ch) = v;  // 8B aligned
            }
        }
        __syncthreads();

        // ---- branch-free sampling from LDS (packed-f32 lerp) ----
        // px,py >= 0 by bbox construction -> truncation == floor, fract valid
        const int kst = k0 + klr;
        v2f pos = {fmaf(c, (float)kst - t_off, bxu) - (float)x0,
                   fmaf(s, (float)kst - t_off, byu) - (float)y0};
        #pragma unroll 4
        for (int k = kst; k <= k1; k += 8) {
            int xi = (int)pos.x;
            int yi = (int)pos.y;
            float wx = __builtin_amdgcn_fractf(pos.x);
            float wy = __builtin_amdgcn_fractf(pos.y);
            int idx = __mul24(yi, PITCH) + xi;
            v2f c0 = {tile[idx],     tile[idx + PITCH]};      // ds_read2 (0,106)
            v2f c1 = {tile[idx + 1], tile[idx + PITCH + 1]};  // ds_read2 (1,107)
            v2f diff = c1 - c0;                               // v_pk_add (neg)
            v2f wx2 = {wx, wx};
            v2f tb = __builtin_elementwise_fma(wx2, diff, c0);  // (top, bot)
            acc = fmaf(wy, tb.y - tb.x, acc + tb.x);
            pos += dinc;                                      // v_pk_add
        }
        __syncthreads();
    }

    // ---- reduce 8 k-residues per detector ----
    acc += __shfl_xor(acc, 16);
    acc += __shfl_xor(acc, 32);
    float* scratch = tile;
    if (l < 16) scratch[w * 16 + l] = acc;
    __syncthreads();
    if (tid < DET_TILE) {
        int g  = tid >> 4;
        int dd = tid & 15;
        float r = scratch[g * 16 + dd] + scratch[(g + 4) * 16 + dd];
        int dglob = d0 + tid;
        if (dglob < N_DET) sino[a * N_DET + dglob] = r;   // last block: dets 736..767 phantom
    }
}

// ---------------------------------------------------------------------------
extern "C" void kernel_launch(void* const* d_in, const int* in_sizes, int n_in,
                              void* d_out, int out_size, void* d_ws, size_t ws_size,
                              hipStream_t stream) {
    const float* x      = (const float*)d_in[0];
    const float* reco   = (const float*)d_in[1];
    const float* angles = (const float*)d_in[2];

    float* sino    = (float*)d_out;              // (360, 736)
    float* updated = (float*)d_out + SINO_SIZE;  // (512, 512)

    int n4 = (H * W) / 4;
    add_kernel<<<n4 / 256, 256, 0, stream>>>(
        (const float4*)x, (const float4*)reco, (float4*)updated);

    dim3 grid((N_DET + DET_TILE - 1) / DET_TILE, N_ANGLES);   // (12, 360)
    radon_kernel<<<grid, 512, 0, stream>>>(updated, angles, sino);
}